// Round 16
// baseline (142.602 us; speedup 1.0000x reference)
//
#include <hip/hip_runtime.h>
#include <hip/hip_bf16.h>
#include <cstdint>

typedef __bf16 bf16x8 __attribute__((ext_vector_type(8)));
typedef float f32x4 __attribute__((ext_vector_type(4)));

__device__ inline unsigned short f2bf(float f) {
  union { float f; unsigned u; } x; x.f = f;
  unsigned r = x.u + 0x7fffu + ((x.u >> 16) & 1u);
  return (unsigned short)(r >> 16);
}
__device__ inline float bf2f(unsigned short b) {
  union { unsigned u; float f; } x; x.u = ((unsigned)b) << 16;
  return x.f;
}

__device__ inline void gload_lds16(const void* g, void* l) {
  __builtin_amdgcn_global_load_lds(
      (const __attribute__((address_space(1))) unsigned int*)g,
      (__attribute__((address_space(3))) unsigned int*)l, 16, 0, 0);
}

// ---------------- QKV (r16): BM=256 x BN=128, 512 threads, 8 waves ----------
// Same per-wave geometry & schedule as r13/r15 (64x64 wave tile, acc[4][4],
// 32 MFMA/K-step, single 48KB image, vmcnt(0)-prefetch-distance schedule,
// XOR swizzle) but: 6 gloads/thread/K-step (25% fewer staged bytes/FLOP) and
// grid 768 = EXACTLY 3 blocks/CU: 48KB*3=144<=160KB LDS, 84VGPR -> 24
// waves/CU -> whole grid co-resident in one wave-pack (no round quantization).
// Decode: x=id&7 (XCD), k=id>>3 in [0,96): bx=(x<<2)|(k&3) in [0,32) (4 row
// panels/XCD = 1024 rows = 2MB xb slice, L2-fit); rest=k>>2: by=rest&7,
// w=rest>>3 (0 K,1 Q,2 V->transposed).
__global__ __launch_bounds__(512) void gemmQ(
    const unsigned short* __restrict__ A,
    const unsigned short* __restrict__ W,
    void* __restrict__ C0,
    const float* __restrict__ b0, const float* __restrict__ b1, const float* __restrict__ b2,
    void* __restrict__ C1, void* __restrict__ C2)
{
  __shared__ unsigned short As[16384];   // [256][64]
  __shared__ unsigned short Bs[8192];    // [128][64]

  const int tid = threadIdx.x;
  const int wid = tid >> 6, lane = tid & 63;
  const int wr = wid >> 1, wc = wid & 1;         // 4M x 2N waves
  const int frow = lane & 15, fk = (lane >> 4) * 8;
  const int swz = (frow & 7) << 3;

  const int id = blockIdx.x;
  const int x = id & 7, k = id >> 3;      // k in [0,96)
  const int bx = (x << 2) | (k & 3);      // [0,32)
  const int rest = k >> 2;                // [0,24)
  const int by = rest & 7, w = rest >> 3;

  const int brow0 = bx * 256, bcol0 = by * 128;
  const unsigned short* Ap = A;
  const unsigned short* Bp = W + ((size_t)w << 20);

  // hoisted staging addresses: A 4 iters, B 2 iters
  const unsigned short* aSrc[4];
  const unsigned short* bSrc[2];
  unsigned short* aDst[4];
  unsigned short* bDst[2];
  #pragma unroll
  for (int i = 0; i < 4; ++i) {
    const int e = (i * 512 + tid) * 8;       // [0,16384)
    const int r = e >> 6, c = e & 63;
    aSrc[i] = Ap + (size_t)(brow0 + r) * 1024 + (c ^ ((r & 7) << 3));
    aDst[i] = &As[e];
  }
  #pragma unroll
  for (int i = 0; i < 2; ++i) {
    const int e = (i * 512 + tid) * 8;       // [0,8192)
    const int r = e >> 6, c = e & 63;
    bSrc[i] = Bp + (size_t)(bcol0 + r) * 1024 + (c ^ ((r & 7) << 3));
    bDst[i] = &Bs[e];
  }

  auto stage = [&](int t) {
    const int k0 = t << 6;
    #pragma unroll
    for (int i = 0; i < 4; ++i) gload_lds16(aSrc[i] + k0, aDst[i]);
    #pragma unroll
    for (int i = 0; i < 2; ++i) gload_lds16(bSrc[i] + k0, bDst[i]);
  };

  f32x4 acc[4][4];
  #pragma unroll
  for (int i = 0; i < 4; ++i)
    #pragma unroll
    for (int j = 0; j < 4; ++j) acc[i][j] = (f32x4){0.f, 0.f, 0.f, 0.f};

  stage(0);

  #pragma unroll 1
  for (int t = 0; t < 16; ++t) {
    asm volatile("s_waitcnt vmcnt(0)" ::: "memory");   // stage(t), issued ~1 iter ago
    __builtin_amdgcn_sched_barrier(0);
    __builtin_amdgcn_s_barrier();
    __builtin_amdgcn_sched_barrier(0);

    bf16x8 af[2][4], bfr[2][4];
    #pragma unroll
    for (int kk = 0; kk < 2; ++kk) {
      const int col = (kk * 32 + fk) ^ swz;
      #pragma unroll
      for (int mi = 0; mi < 4; ++mi)
        af[kk][mi] = *(const bf16x8*)&As[(wr * 64 + mi * 16 + frow) * 64 + col];
      #pragma unroll
      for (int ni = 0; ni < 4; ++ni)
        bfr[kk][ni] = *(const bf16x8*)&Bs[(wc * 64 + ni * 16 + frow) * 64 + col];
    }
    asm volatile("s_waitcnt lgkmcnt(0)" ::: "memory");
    __builtin_amdgcn_sched_barrier(0);
    __builtin_amdgcn_s_barrier();
    __builtin_amdgcn_sched_barrier(0);

    if (t + 1 < 16) stage(t + 1);

    __builtin_amdgcn_s_setprio(1);
    #pragma unroll
    for (int kk = 0; kk < 2; ++kk)
      #pragma unroll
      for (int mi = 0; mi < 4; ++mi)
        #pragma unroll
        for (int ni = 0; ni < 4; ++ni)
          acc[mi][ni] = __builtin_amdgcn_mfma_f32_16x16x32_bf16(af[kk][mi], bfr[kk][ni], acc[mi][ni], 0, 0, 0);
    __builtin_amdgcn_s_setprio(0);
  }

  const float* bias = (w == 0) ? b0 : (w == 1) ? b1 : b2;
  #pragma unroll
  for (int mi = 0; mi < 4; ++mi) {
    #pragma unroll
    for (int ni = 0; ni < 4; ++ni) {
      const int row0 = brow0 + wr * 64 + mi * 16 + (lane >> 4) * 4;
      const int col = bcol0 + wc * 64 + ni * 16 + frow;
      const float bv = bias[col];
      if (w == 2) {
        unsigned short* Cb = (unsigned short*)C2;
        const int bb = row0 >> 11, s0 = row0 & 2047;
        ushort4 pk;
        pk.x = f2bf(acc[mi][ni][0] + bv);
        pk.y = f2bf(acc[mi][ni][1] + bv);
        pk.z = f2bf(acc[mi][ni][2] + bv);
        pk.w = f2bf(acc[mi][ni][3] + bv);
        *(ushort4*)&Cb[(size_t)bb * (1024 * 2048) + (size_t)col * 2048 + s0] = pk;
      } else {
        unsigned short* Cb = (unsigned short*)(w == 0 ? C0 : C1);
        #pragma unroll
        for (int r = 0; r < 4; ++r)
          Cb[(size_t)(row0 + r) * 1024 + col] = f2bf(acc[mi][ni][r] + bv);
      }
    }
  }
}

// ---------- scores/PV: r15-identical m97 GEMM (proven 132.2 us path) ----------
template <int MODE>
__global__ __launch_bounds__(256) void gemmC(
    const unsigned short* __restrict__ A, int lda, long long sA,
    const unsigned short* __restrict__ B0, int ldb, long long sB,
    void* __restrict__ C0, int ldc, long long sC,
    int K, float scale)
{
  __shared__ unsigned short As[8192];   // [128][64]
  __shared__ unsigned short Bs[8192];

  const int tid = threadIdx.x;
  const int wid = tid >> 6, lane = tid & 63;
  const int wr = wid >> 1, wc = wid & 1;
  const int frow = lane & 15, fk = (lane >> 4) * 8;
  const int swz = (frow & 7) << 3;

  const int id = blockIdx.x;
  int bx, by, bz;
  if (MODE == 2) {
    const int x = id & 7;
    bz = x & 3;
    int u = ((id >> 3) << 1) | (x >> 2);    // [0,136) triangular index
    int r = (int)((sqrtf(8.f * u + 1.f) - 1.f) * 0.5f);
    while ((r + 1) * (r + 2) / 2 <= u) ++r;
    while (r * (r + 1) / 2 > u) --r;
    bx = r; by = u - r * (r + 1) / 2;       // by <= bx
  } else {
    const int x = id & 7, g = id >> 3;      // g in [0,64)
    bz = x & 3;
    by = g & 7;
    bx = ((7 - (g >> 3)) << 1) | (x >> 2);  // [0,16), LPT
  }

  const int brow0 = bx * 128, bcol0 = by * 128;
  const unsigned short* Ap = A + (size_t)bz * sA;
  const unsigned short* Bp = B0 + (size_t)bz * sB;
  const int kend = (MODE == 3) ? min(K, brow0 + 128) : K;
  const int nt = kend >> 6;

  const unsigned short* aSrc[4];
  const unsigned short* bSrc[4];
  unsigned short* aDst[4];
  unsigned short* bDst[4];
  #pragma unroll
  for (int i = 0; i < 4; ++i) {
    const int e = (i * 256 + tid) * 8;
    const int r = e >> 6, c = e & 63;
    const int sc = c ^ ((r & 7) << 3);
    aSrc[i] = Ap + (size_t)(brow0 + r) * lda + sc;
    bSrc[i] = Bp + (size_t)(bcol0 + r) * ldb + sc;
    aDst[i] = &As[e];
    bDst[i] = &Bs[e];
  }

  auto stage = [&](int t) {
    const int k0 = t << 6;
    #pragma unroll
    for (int i = 0; i < 4; ++i) gload_lds16(aSrc[i] + k0, aDst[i]);
    #pragma unroll
    for (int i = 0; i < 4; ++i) gload_lds16(bSrc[i] + k0, bDst[i]);
  };

  f32x4 acc[4][4];
  #pragma unroll
  for (int i = 0; i < 4; ++i)
    #pragma unroll
    for (int j = 0; j < 4; ++j) acc[i][j] = (f32x4){0.f, 0.f, 0.f, 0.f};

  stage(0);

  #pragma unroll 1
  for (int t = 0; t < nt; ++t) {
    asm volatile("s_waitcnt vmcnt(0)" ::: "memory");
    __builtin_amdgcn_sched_barrier(0);
    __builtin_amdgcn_s_barrier();
    __builtin_amdgcn_sched_barrier(0);

    bf16x8 af[2][4], bfr[2][4];
    #pragma unroll
    for (int kk = 0; kk < 2; ++kk) {
      const int col = (kk * 32 + fk) ^ swz;
      #pragma unroll
      for (int mi = 0; mi < 4; ++mi)
        af[kk][mi] = *(const bf16x8*)&As[(wr * 64 + mi * 16 + frow) * 64 + col];
      #pragma unroll
      for (int ni = 0; ni < 4; ++ni)
        bfr[kk][ni] = *(const bf16x8*)&Bs[(wc * 64 + ni * 16 + frow) * 64 + col];
    }
    asm volatile("s_waitcnt lgkmcnt(0)" ::: "memory");
    __builtin_amdgcn_sched_barrier(0);
    __builtin_amdgcn_s_barrier();
    __builtin_amdgcn_sched_barrier(0);

    if (t + 1 < nt) stage(t + 1);

    __builtin_amdgcn_s_setprio(1);
    #pragma unroll
    for (int kk = 0; kk < 2; ++kk)
      #pragma unroll
      for (int mi = 0; mi < 4; ++mi)
        #pragma unroll
        for (int ni = 0; ni < 4; ++ni)
          acc[mi][ni] = __builtin_amdgcn_mfma_f32_16x16x32_bf16(af[kk][mi], bfr[kk][ni], acc[mi][ni], 0, 0, 0);
    __builtin_amdgcn_s_setprio(0);
  }

  #pragma unroll
  for (int mi = 0; mi < 4; ++mi) {
    #pragma unroll
    for (int ni = 0; ni < 4; ++ni) {
      const int row0 = brow0 + wr * 64 + mi * 16 + (lane >> 4) * 4;
      const int col = bcol0 + wc * 64 + ni * 16 + frow;
      if (MODE == 2) {
        unsigned short* Cb = (unsigned short*)C0 + (size_t)bz * sC;
        #pragma unroll
        for (int r = 0; r < 4; ++r)
          Cb[(size_t)(row0 + r) * ldc + col] = f2bf(acc[mi][ni][r] * scale);
      } else {
        float* Cf = (float*)C0 + (size_t)bz * sC;
        #pragma unroll
        for (int r = 0; r < 4; ++r)
          Cf[(size_t)(row0 + r) * ldc + col] = acc[mi][ni][r];
      }
    }
  }
}

// in-place causal softmax, trimmed to the 128-col-rounded causal prefix
__global__ __launch_bounds__(256) void softmax_causal(unsigned short* __restrict__ Sc) {
  const int row = blockIdx.x;     // b*2048 + i
  const int i = row & 2047;
  const int nc = ((i >> 7) + 1) * 128;
  unsigned short* rp = Sc + (size_t)row * 2048;
  const int t = threadIdx.x;
  const int j0 = t * 8;
  const bool act = (j0 < nc);

  float v[8];
  if (act) {
    uint4 raw = ((const uint4*)rp)[t];
    unsigned us[8];
    us[0] = raw.x & 0xffffu; us[1] = raw.x >> 16;
    us[2] = raw.y & 0xffffu; us[3] = raw.y >> 16;
    us[4] = raw.z & 0xffffu; us[5] = raw.z >> 16;
    us[6] = raw.w & 0xffffu; us[7] = raw.w >> 16;
    #pragma unroll
    for (int e = 0; e < 8; ++e) v[e] = bf2f((unsigned short)us[e]);
  } else {
    #pragma unroll
    for (int e = 0; e < 8; ++e) v[e] = 0.f;
  }

  float m = -3.0e38f;
  if (act) {
    #pragma unroll
    for (int e = 0; e < 8; ++e) if (j0 + e <= i) m = fmaxf(m, v[e]);
  }
  #pragma unroll
  for (int o = 32; o > 0; o >>= 1) m = fmaxf(m, __shfl_xor(m, o));

  __shared__ float red[8];
  const int wid = t >> 6, lane = t & 63;
  if (lane == 0) red[wid] = m;
  __syncthreads();
  m = fmaxf(fmaxf(red[0], red[1]), fmaxf(red[2], red[3]));

  float ev[8];
  float s = 0.f;
  #pragma unroll
  for (int e = 0; e < 8; ++e) {
    float x = (act && j0 + e <= i) ? __expf(v[e] - m) : 0.f;
    ev[e] = x; s += x;
  }
  #pragma unroll
  for (int o = 32; o > 0; o >>= 1) s += __shfl_xor(s, o);
  if (lane == 0) red[4 + wid] = s;
  __syncthreads();
  s = red[4] + red[5] + red[6] + red[7];
  const float inv = 1.f / s;

  if (act) {
    uint4 outw;
    outw.x = (unsigned)f2bf(ev[0] * inv) | ((unsigned)f2bf(ev[1] * inv) << 16);
    outw.y = (unsigned)f2bf(ev[2] * inv) | ((unsigned)f2bf(ev[3] * inv) << 16);
    outw.z = (unsigned)f2bf(ev[4] * inv) | ((unsigned)f2bf(ev[5] * inv) << 16);
    outw.w = (unsigned)f2bf(ev[6] * inv) | ((unsigned)f2bf(ev[7] * inv) << 16);
    ((uint4*)rp)[t] = outw;
  }
}

// one launch converts x (2,097,152 float4) + 3 weights (262,144 float4 each)
__global__ __launch_bounds__(256) void cvt_all(
    const float4* __restrict__ x,
    const float4* __restrict__ w0, const float4* __restrict__ w1,
    const float4* __restrict__ w2,
    ushort4* __restrict__ xb, ushort4* __restrict__ wb) {
  const int idx = blockIdx.x * 256 + threadIdx.x;   // [0, 2883584)
  const float4* src; ushort4* dst; int off;
  if (idx < 2097152) { src = x; dst = xb; off = idx; }
  else {
    const int j = idx - 2097152;
    const int sel = j >> 18;                        // 262144 per weight
    src = (sel == 0) ? w0 : (sel == 1) ? w1 : w2;
    dst = wb + (size_t)sel * 262144;
    off = j & 262143;
  }
  float4 f = src[off];
  ushort4 o;
  o.x = f2bf(f.x); o.y = f2bf(f.y); o.z = f2bf(f.z); o.w = f2bf(f.w);
  dst[off] = o;
}

extern "C" void kernel_launch(void* const* d_in, const int* in_sizes, int n_in,
                              void* d_out, int out_size, void* d_ws, size_t ws_size,
                              hipStream_t stream) {
  const float* x  = (const float*)d_in[0];
  const float* Wk = (const float*)d_in[1];
  const float* bk = (const float*)d_in[2];
  const float* Wq = (const float*)d_in[3];
  const float* bq = (const float*)d_in[4];
  const float* Wv = (const float*)d_in[5];
  const float* bv = (const float*)d_in[6];
  float* out = (float*)d_out;

  char* ws = (char*)d_ws;
  unsigned short* xb = (unsigned short*)(ws + 0);          // 8192x1024 bf16  (16 MB)
  unsigned short* Wb = (unsigned short*)(ws + 16777216);   // 3 x 1024x1024   (6 MB)
  unsigned short* Kb = (unsigned short*)(ws + 23068672);   // 8192x1024       (16 MB)
  unsigned short* Qb = (unsigned short*)(ws + 39845888);   // 8192x1024       (16 MB)
  unsigned short* Vt = (unsigned short*)(ws + 56623104);   // 4 x 1024x2048   (16 MB)
  unsigned short* Sc = (unsigned short*)(ws + 73400320);   // 4 x 2048x2048   (32 MB)

  // converts (x + 3 weights, one launch)
  cvt_all<<<11264, 256, 0, stream>>>((const float4*)x, (const float4*)Wk,
                                     (const float4*)Wq, (const float4*)Wv,
                                     (ushort4*)xb, (ushort4*)Wb);

  // fused QKV: 768 blocks x 512 threads (3 blocks/CU, whole grid co-resident)
  gemmQ<<<768, 512, 0, stream>>>(xb, Wb, Kb, bk, bq, bv, Qb, Vt);

  // scores = Q K^T / 32: exact causal lower-triangle grid (544 blocks)
  gemmC<2><<<544, 256, 0, stream>>>(
      Qb, 1024, 2048LL * 1024, Kb, 1024, 2048LL * 1024,
      Sc, 2048, 2048LL * 2048, 1024, 0.03125f);

  softmax_causal<<<8192, 256, 0, stream>>>(Sc);

  // out = P @ V: 512 blocks, LPT, XCD-pinned batch (Vt L2-resident)
  gemmC<3><<<512, 256, 0, stream>>>(
      Sc, 2048, 2048LL * 2048, Vt, 2048, 1024LL * 2048,
      out, 1024, 2048LL * 1024, 2048, 1.f);
}

// Round 17
// 140.819 us; speedup vs baseline: 1.0127x; 1.0127x over previous
//
#include <hip/hip_runtime.h>
#include <hip/hip_bf16.h>
#include <cstdint>

typedef __bf16 bf16x8 __attribute__((ext_vector_type(8)));
typedef float f32x4 __attribute__((ext_vector_type(4)));

__device__ inline unsigned short f2bf(float f) {
  union { float f; unsigned u; } x; x.f = f;
  unsigned r = x.u + 0x7fffu + ((x.u >> 16) & 1u);
  return (unsigned short)(r >> 16);
}
__device__ inline float bf2f(unsigned short b) {
  union { unsigned u; float f; } x; x.u = ((unsigned)b) << 16;
  return x.f;
}

__device__ inline void gload_lds16(const void* g, void* l) {
  __builtin_amdgcn_global_load_lds(
      (const __attribute__((address_space(1))) unsigned int*)g,
      (__attribute__((address_space(3))) unsigned int*)l, 16, 0, 0);
}

// r17 = r15 (132.2 us proven) + counted-lgkmcnt split MFMA.
// m97-geometry GEMM, prefetched single-image schedule:
// BM=BN=128, BK=64, 4 waves (2x2, wave tile 64x64), 32 KB single LDS image,
// XOR-swizzle (L(r,c)=G(r, c^((r&7)<<3)), 0-conflict proven).
// Per K-step:
//   vmcnt(0)        <- stage(t), issued ONE iteration ago (prefetch distance)
//   barrier1        <- tile visible block-wide
//   issue kk0 reads (8 ds_read_b128), then kk1 reads (8)
//   lgkmcnt(8)      <- kk0 frags landed (DS retire in-order); kk1 in flight
//   16 MFMA (kk0)   <- overlaps kk1 read completion
//   lgkmcnt(0)      <- kk1 landed (free: completed under kk0 MFMA)
//   barrier2        <- image free for restage
//   stage(t+1); 16 MFMA (kk1) overlap staging
// vs r15: the full 16-read drain is no longer exposed; ~100-190 cyc/step
// of ds_read latency hides under kk0's MFMA cluster.
// Grids: MODE 0 QKV 1536 blocks XCD-chunked; MODE 2 scores 544 blocks exact
// lower-triangle; MODE 3 PV 512 blocks LPT, XCD-pinned batch, kend=(bx+1)*128.
template <int MODE>
__global__ __launch_bounds__(256) void gemmC(
    const unsigned short* __restrict__ A, int lda, long long sA,
    const unsigned short* __restrict__ B0, int ldb, long long sB,
    void* __restrict__ C0, int ldc, long long sC,
    const float* __restrict__ b0, const float* __restrict__ b1, const float* __restrict__ b2,
    void* __restrict__ C1, void* __restrict__ C2,
    int K, float scale)
{
  __shared__ unsigned short As[8192];   // [128][64]
  __shared__ unsigned short Bs[8192];

  const int tid = threadIdx.x;
  const int wid = tid >> 6, lane = tid & 63;
  const int wr = wid >> 1, wc = wid & 1;
  const int frow = lane & 15, fk = (lane >> 4) * 8;
  const int swz = (frow & 7) << 3;

  const int id = blockIdx.x;
  int bx, by, bz = 0, w = 0;
  if (MODE == 0) {
    const int x = id & 7, k = id >> 3;      // k in [0,192)
    bx = (x << 3) | (k & 7);                // [0,64)
    by = k >> 3;                            // [0,24)
    w = by >> 3; by &= 7;
  } else if (MODE == 2) {
    const int x = id & 7;
    bz = x & 3;
    int u = ((id >> 3) << 1) | (x >> 2);    // [0,136) triangular index
    int r = (int)((sqrtf(8.f * u + 1.f) - 1.f) * 0.5f);
    while ((r + 1) * (r + 2) / 2 <= u) ++r;
    while (r * (r + 1) / 2 > u) --r;
    bx = r; by = u - r * (r + 1) / 2;       // by <= bx
  } else {
    const int x = id & 7, g = id >> 3;      // g in [0,64)
    bz = x & 3;
    by = g & 7;
    bx = ((7 - (g >> 3)) << 1) | (x >> 2);  // [0,16), LPT
  }

  const int brow0 = bx * 128, bcol0 = by * 128;
  const unsigned short *Ap, *Bp;
  if (MODE == 0) {
    Ap = A;
    Bp = B0 + ((size_t)w << 20);
  } else {
    Ap = A + (size_t)bz * sA;
    Bp = B0 + (size_t)bz * sB;
  }
  const int kend = (MODE == 3) ? min(K, brow0 + 128) : K;
  const int nt = kend >> 6;

  // hoisted staging addresses (loop-invariant; stage(t) adds k0 only)
  const unsigned short* aSrc[4];
  const unsigned short* bSrc[4];
  unsigned short* aDst[4];
  unsigned short* bDst[4];
  #pragma unroll
  for (int i = 0; i < 4; ++i) {
    const int e = (i * 256 + tid) * 8;
    const int r = e >> 6, c = e & 63;
    const int sc = c ^ ((r & 7) << 3);
    aSrc[i] = Ap + (size_t)(brow0 + r) * lda + sc;
    bSrc[i] = Bp + (size_t)(bcol0 + r) * ldb + sc;
    aDst[i] = &As[e];
    bDst[i] = &Bs[e];
  }

  auto stage = [&](int t) {
    const int k0 = t << 6;
    #pragma unroll
    for (int i = 0; i < 4; ++i) gload_lds16(aSrc[i] + k0, aDst[i]);
    #pragma unroll
    for (int i = 0; i < 4; ++i) gload_lds16(bSrc[i] + k0, bDst[i]);
  };

  f32x4 acc[4][4];
  #pragma unroll
  for (int i = 0; i < 4; ++i)
    #pragma unroll
    for (int j = 0; j < 4; ++j) acc[i][j] = (f32x4){0.f, 0.f, 0.f, 0.f};

  stage(0);   // prologue: only exposed-latency stage of the block

  const int col0 = fk ^ swz;          // kk=0 read column
  const int col1 = (32 + fk) ^ swz;   // kk=1 (XOR, not +, per r5 lesson)

  #pragma unroll 1
  for (int t = 0; t < nt; ++t) {
    asm volatile("s_waitcnt vmcnt(0)" ::: "memory");   // own stage(t) landed (issued ~1 iter ago)
    __builtin_amdgcn_sched_barrier(0);
    __builtin_amdgcn_s_barrier();                      // whole tile visible to all waves
    __builtin_amdgcn_sched_barrier(0);

    bf16x8 af0[4], bf0[4], af1[4], bf1[4];
    // kk0 reads first (their lgkm retire unblocks the kk0 MFMA cluster)
    #pragma unroll
    for (int mi = 0; mi < 4; ++mi)
      af0[mi] = *(const bf16x8*)&As[(wr * 64 + mi * 16 + frow) * 64 + col0];
    #pragma unroll
    for (int ni = 0; ni < 4; ++ni)
      bf0[ni] = *(const bf16x8*)&Bs[(wc * 64 + ni * 16 + frow) * 64 + col0];
    __builtin_amdgcn_sched_barrier(0);                 // pin issue order: kk0 before kk1
    #pragma unroll
    for (int mi = 0; mi < 4; ++mi)
      af1[mi] = *(const bf16x8*)&As[(wr * 64 + mi * 16 + frow) * 64 + col1];
    #pragma unroll
    for (int ni = 0; ni < 4; ++ni)
      bf1[ni] = *(const bf16x8*)&Bs[(wc * 64 + ni * 16 + frow) * 64 + col1];
    __builtin_amdgcn_sched_barrier(0);

    asm volatile("s_waitcnt lgkmcnt(8)" ::: "memory"); // kk0's 8 landed; kk1's 8 in flight
    __builtin_amdgcn_sched_barrier(0);
    __builtin_amdgcn_s_setprio(1);
    #pragma unroll
    for (int mi = 0; mi < 4; ++mi)
      #pragma unroll
      for (int ni = 0; ni < 4; ++ni)
        acc[mi][ni] = __builtin_amdgcn_mfma_f32_16x16x32_bf16(af0[mi], bf0[ni], acc[mi][ni], 0, 0, 0);
    __builtin_amdgcn_s_setprio(0);
    __builtin_amdgcn_sched_barrier(0);

    asm volatile("s_waitcnt lgkmcnt(0)" ::: "memory"); // kk1 landed (under kk0 MFMA)
    __builtin_amdgcn_sched_barrier(0);
    __builtin_amdgcn_s_barrier();                      // image free for restage
    __builtin_amdgcn_sched_barrier(0);

    if (t + 1 < nt) stage(t + 1);                      // overlaps with kk1 MFMA below

    __builtin_amdgcn_s_setprio(1);
    #pragma unroll
    for (int mi = 0; mi < 4; ++mi)
      #pragma unroll
      for (int ni = 0; ni < 4; ++ni)
        acc[mi][ni] = __builtin_amdgcn_mfma_f32_16x16x32_bf16(af1[mi], bf1[ni], acc[mi][ni], 0, 0, 0);
    __builtin_amdgcn_s_setprio(0);
  }

  // epilogue: C/D layout col=lane&15, row=(lane>>4)*4+reg
  const float* bias = nullptr;
  if (MODE == 0) bias = (w == 0) ? b0 : (w == 1) ? b1 : b2;

  #pragma unroll
  for (int mi = 0; mi < 4; ++mi) {
    #pragma unroll
    for (int ni = 0; ni < 4; ++ni) {
      const int row0 = brow0 + wr * 64 + mi * 16 + (lane >> 4) * 4;
      const int col = bcol0 + wc * 64 + ni * 16 + frow;
      if (MODE == 0) {
        const float bv = bias[col];
        if (w == 2) {
          unsigned short* Cb = (unsigned short*)C2;
          const int bb = row0 >> 11, s0 = row0 & 2047;
          ushort4 pk;
          pk.x = f2bf(acc[mi][ni][0] + bv);
          pk.y = f2bf(acc[mi][ni][1] + bv);
          pk.z = f2bf(acc[mi][ni][2] + bv);
          pk.w = f2bf(acc[mi][ni][3] + bv);
          *(ushort4*)&Cb[(size_t)bb * (1024 * 2048) + (size_t)col * 2048 + s0] = pk;
        } else {
          unsigned short* Cb = (unsigned short*)(w == 0 ? C0 : C1);
          #pragma unroll
          for (int r = 0; r < 4; ++r)
            Cb[(size_t)(row0 + r) * ldc + col] = f2bf(acc[mi][ni][r] + bv);
        }
      } else if (MODE == 2) {
        unsigned short* Cb = (unsigned short*)C0 + (size_t)bz * sC;
        #pragma unroll
        for (int r = 0; r < 4; ++r)
          Cb[(size_t)(row0 + r) * ldc + col] = f2bf(acc[mi][ni][r] * scale);
      } else {
        float* Cf = (float*)C0 + (size_t)bz * sC;
        #pragma unroll
        for (int r = 0; r < 4; ++r)
          Cf[(size_t)(row0 + r) * ldc + col] = acc[mi][ni][r];
      }
    }
  }
}

// in-place causal softmax, trimmed to the 128-col-rounded causal prefix
__global__ __launch_bounds__(256) void softmax_causal(unsigned short* __restrict__ Sc) {
  const int row = blockIdx.x;     // b*2048 + i
  const int i = row & 2047;
  const int nc = ((i >> 7) + 1) * 128;
  unsigned short* rp = Sc + (size_t)row * 2048;
  const int t = threadIdx.x;
  const int j0 = t * 8;
  const bool act = (j0 < nc);

  float v[8];
  if (act) {
    uint4 raw = ((const uint4*)rp)[t];
    unsigned us[8];
    us[0] = raw.x & 0xffffu; us[1] = raw.x >> 16;
    us[2] = raw.y & 0xffffu; us[3] = raw.y >> 16;
    us[4] = raw.z & 0xffffu; us[5] = raw.z >> 16;
    us[6] = raw.w & 0xffffu; us[7] = raw.w >> 16;
    #pragma unroll
    for (int e = 0; e < 8; ++e) v[e] = bf2f((unsigned short)us[e]);
  } else {
    #pragma unroll
    for (int e = 0; e < 8; ++e) v[e] = 0.f;
  }

  float m = -3.0e38f;
  if (act) {
    #pragma unroll
    for (int e = 0; e < 8; ++e) if (j0 + e <= i) m = fmaxf(m, v[e]);
  }
  #pragma unroll
  for (int o = 32; o > 0; o >>= 1) m = fmaxf(m, __shfl_xor(m, o));

  __shared__ float red[8];
  const int wid = t >> 6, lane = t & 63;
  if (lane == 0) red[wid] = m;
  __syncthreads();
  m = fmaxf(fmaxf(red[0], red[1]), fmaxf(red[2], red[3]));

  float ev[8];
  float s = 0.f;
  #pragma unroll
  for (int e = 0; e < 8; ++e) {
    float x = (act && j0 + e <= i) ? __expf(v[e] - m) : 0.f;
    ev[e] = x; s += x;
  }
  #pragma unroll
  for (int o = 32; o > 0; o >>= 1) s += __shfl_xor(s, o);
  if (lane == 0) red[4 + wid] = s;
  __syncthreads();
  s = red[4] + red[5] + red[6] + red[7];
  const float inv = 1.f / s;

  if (act) {
    uint4 outw;
    outw.x = (unsigned)f2bf(ev[0] * inv) | ((unsigned)f2bf(ev[1] * inv) << 16);
    outw.y = (unsigned)f2bf(ev[2] * inv) | ((unsigned)f2bf(ev[3] * inv) << 16);
    outw.z = (unsigned)f2bf(ev[4] * inv) | ((unsigned)f2bf(ev[5] * inv) << 16);
    outw.w = (unsigned)f2bf(ev[6] * inv) | ((unsigned)f2bf(ev[7] * inv) << 16);
    ((uint4*)rp)[t] = outw;
  }
}

// one launch converts x (2,097,152 float4) + 3 weights (262,144 float4 each)
__global__ __launch_bounds__(256) void cvt_all(
    const float4* __restrict__ x,
    const float4* __restrict__ w0, const float4* __restrict__ w1,
    const float4* __restrict__ w2,
    ushort4* __restrict__ xb, ushort4* __restrict__ wb) {
  const int idx = blockIdx.x * 256 + threadIdx.x;   // [0, 2883584)
  const float4* src; ushort4* dst; int off;
  if (idx < 2097152) { src = x; dst = xb; off = idx; }
  else {
    const int j = idx - 2097152;
    const int sel = j >> 18;                        // 262144 per weight
    src = (sel == 0) ? w0 : (sel == 1) ? w1 : w2;
    dst = wb + (size_t)sel * 262144;
    off = j & 262143;
  }
  float4 f = src[off];
  ushort4 o;
  o.x = f2bf(f.x); o.y = f2bf(f.y); o.z = f2bf(f.z); o.w = f2bf(f.w);
  dst[off] = o;
}

extern "C" void kernel_launch(void* const* d_in, const int* in_sizes, int n_in,
                              void* d_out, int out_size, void* d_ws, size_t ws_size,
                              hipStream_t stream) {
  const float* x  = (const float*)d_in[0];
  const float* Wk = (const float*)d_in[1];
  const float* bk = (const float*)d_in[2];
  const float* Wq = (const float*)d_in[3];
  const float* bq = (const float*)d_in[4];
  const float* Wv = (const float*)d_in[5];
  const float* bv = (const float*)d_in[6];
  float* out = (float*)d_out;

  char* ws = (char*)d_ws;
  unsigned short* xb = (unsigned short*)(ws + 0);          // 8192x1024 bf16  (16 MB)
  unsigned short* Wb = (unsigned short*)(ws + 16777216);   // 3 x 1024x1024   (6 MB)
  unsigned short* Kb = (unsigned short*)(ws + 23068672);   // 8192x1024       (16 MB)
  unsigned short* Qb = (unsigned short*)(ws + 39845888);   // 8192x1024       (16 MB)
  unsigned short* Vt = (unsigned short*)(ws + 56623104);   // 4 x 1024x2048   (16 MB)
  unsigned short* Sc = (unsigned short*)(ws + 73400320);   // 4 x 2048x2048   (32 MB)

  // converts (x + 3 weights, one launch)
  cvt_all<<<11264, 256, 0, stream>>>((const float4*)x, (const float4*)Wk,
                                     (const float4*)Wq, (const float4*)Wv,
                                     (ushort4*)xb, (ushort4*)Wb);

  // fused QKV: 1536 blocks, XCD-chunked row panels
  gemmC<0><<<1536, 256, 0, stream>>>(
      xb, 1024, 0, Wb, 1024, 0, Kb, 1024, 0, bk, bq, bv, Qb, Vt, 1024, 1.f);

  // scores = Q K^T / 32: exact causal lower-triangle grid (544 blocks)
  gemmC<2><<<544, 256, 0, stream>>>(
      Qb, 1024, 2048LL * 1024, Kb, 1024, 2048LL * 1024,
      Sc, 2048, 2048LL * 2048, nullptr, nullptr, nullptr, nullptr, nullptr, 1024, 0.03125f);

  softmax_causal<<<8192, 256, 0, stream>>>(Sc);

  // out = P @ V: 512 blocks, LPT, XCD-pinned batch (Vt L2-resident)
  gemmC<3><<<512, 256, 0, stream>>>(
      Sc, 2048, 2048LL * 2048, Vt, 2048, 1024LL * 2048,
      out, 1024, 2048LL * 1024, nullptr, nullptr, nullptr, nullptr, nullptr, 2048, 1.f);
}

// Round 18
// 132.151 us; speedup vs baseline: 1.0791x; 1.0656x over previous
//
#include <hip/hip_runtime.h>
#include <hip/hip_bf16.h>
#include <cstdint>

typedef __bf16 bf16x8 __attribute__((ext_vector_type(8)));
typedef float f32x4 __attribute__((ext_vector_type(4)));

__device__ inline unsigned short f2bf(float f) {
  union { float f; unsigned u; } x; x.f = f;
  unsigned r = x.u + 0x7fffu + ((x.u >> 16) & 1u);
  return (unsigned short)(r >> 16);
}
__device__ inline float bf2f(unsigned short b) {
  union { unsigned u; float f; } x; x.u = ((unsigned)b) << 16;
  return x.f;
}

__device__ inline void gload_lds16(const void* g, void* l) {
  __builtin_amdgcn_global_load_lds(
      (const __attribute__((address_space(1))) unsigned int*)g,
      (__attribute__((address_space(3))) unsigned int*)l, 16, 0, 0);
}

// r18 = r15 exact revert (132.2 us proven best).
// m97-geometry GEMM, prefetched single-image schedule:
// BM=BN=128, BK=64, 4 waves (2x2, wave tile 64x64), 32 KB single LDS image,
// XOR-swizzle (L(r,c)=G(r, c^((r&7)<<3)), 0-conflict proven).
// Per K-step: vmcnt(0) [stage(t) issued ONE iteration ago — ~32-MFMA
// prefetch distance] -> barrier -> 16 ds_read frags -> lgkmcnt(0) ->
// barrier -> stage(t+1) into same image -> 32-MFMA setprio cluster.
// Structural-variant scorecard (all measured, all lost to this schedule):
//   LDS-free streaming (r10, -123us), cvt-fold reg-stage A (r11, -29),
//   BN=256 wide tile (r12, -18), double-image 1-barrier (r14, -6),
//   512-thr BM=256 (r16, -14), counted-lgkm split (r17, -8.6),
//   8-phase 256^2 ports (r4-r7, -30..-45).
// Grids: MODE 0 QKV 1536 blocks XCD-chunked; MODE 2 scores 544 blocks exact
// lower-triangle; MODE 3 PV 512 blocks LPT, XCD-pinned batch, kend=(bx+1)*128.
template <int MODE>
__global__ __launch_bounds__(256) void gemmC(
    const unsigned short* __restrict__ A, int lda, long long sA,
    const unsigned short* __restrict__ B0, int ldb, long long sB,
    void* __restrict__ C0, int ldc, long long sC,
    const float* __restrict__ b0, const float* __restrict__ b1, const float* __restrict__ b2,
    void* __restrict__ C1, void* __restrict__ C2,
    int K, float scale)
{
  __shared__ unsigned short As[8192];   // [128][64]
  __shared__ unsigned short Bs[8192];

  const int tid = threadIdx.x;
  const int wid = tid >> 6, lane = tid & 63;
  const int wr = wid >> 1, wc = wid & 1;
  const int frow = lane & 15, fk = (lane >> 4) * 8;
  const int swz = (frow & 7) << 3;

  const int id = blockIdx.x;
  int bx, by, bz = 0, w = 0;
  if (MODE == 0) {
    const int x = id & 7, k = id >> 3;      // k in [0,192)
    bx = (x << 3) | (k & 7);                // [0,64)
    by = k >> 3;                            // [0,24)
    w = by >> 3; by &= 7;
  } else if (MODE == 2) {
    const int x = id & 7;
    bz = x & 3;
    int u = ((id >> 3) << 1) | (x >> 2);    // [0,136) triangular index
    int r = (int)((sqrtf(8.f * u + 1.f) - 1.f) * 0.5f);
    while ((r + 1) * (r + 2) / 2 <= u) ++r;
    while (r * (r + 1) / 2 > u) --r;
    bx = r; by = u - r * (r + 1) / 2;       // by <= bx
  } else {
    const int x = id & 7, g = id >> 3;      // g in [0,64)
    bz = x & 3;
    by = g & 7;
    bx = ((7 - (g >> 3)) << 1) | (x >> 2);  // [0,16), LPT
  }

  const int brow0 = bx * 128, bcol0 = by * 128;
  const unsigned short *Ap, *Bp;
  if (MODE == 0) {
    Ap = A;
    Bp = B0 + ((size_t)w << 20);
  } else {
    Ap = A + (size_t)bz * sA;
    Bp = B0 + (size_t)bz * sB;
  }
  const int kend = (MODE == 3) ? min(K, brow0 + 128) : K;
  const int nt = kend >> 6;

  // hoisted staging addresses (loop-invariant; stage(t) adds k0 only)
  const unsigned short* aSrc[4];
  const unsigned short* bSrc[4];
  unsigned short* aDst[4];
  unsigned short* bDst[4];
  #pragma unroll
  for (int i = 0; i < 4; ++i) {
    const int e = (i * 256 + tid) * 8;
    const int r = e >> 6, c = e & 63;
    const int sc = c ^ ((r & 7) << 3);
    aSrc[i] = Ap + (size_t)(brow0 + r) * lda + sc;
    bSrc[i] = Bp + (size_t)(bcol0 + r) * ldb + sc;
    aDst[i] = &As[e];
    bDst[i] = &Bs[e];
  }

  auto stage = [&](int t) {
    const int k0 = t << 6;
    #pragma unroll
    for (int i = 0; i < 4; ++i) gload_lds16(aSrc[i] + k0, aDst[i]);
    #pragma unroll
    for (int i = 0; i < 4; ++i) gload_lds16(bSrc[i] + k0, bDst[i]);
  };

  f32x4 acc[4][4];
  #pragma unroll
  for (int i = 0; i < 4; ++i)
    #pragma unroll
    for (int j = 0; j < 4; ++j) acc[i][j] = (f32x4){0.f, 0.f, 0.f, 0.f};

  stage(0);   // prologue: only exposed-latency stage of the block

  #pragma unroll 1
  for (int t = 0; t < nt; ++t) {
    asm volatile("s_waitcnt vmcnt(0)" ::: "memory");   // own stage(t) landed (issued ~1 iter ago)
    __builtin_amdgcn_sched_barrier(0);
    __builtin_amdgcn_s_barrier();                      // whole tile visible to all waves
    __builtin_amdgcn_sched_barrier(0);

    bf16x8 af[2][4], bfr[2][4];
    #pragma unroll
    for (int kk = 0; kk < 2; ++kk) {
      const int col = (kk * 32 + fk) ^ swz;
      #pragma unroll
      for (int mi = 0; mi < 4; ++mi)
        af[kk][mi] = *(const bf16x8*)&As[(wr * 64 + mi * 16 + frow) * 64 + col];
      #pragma unroll
      for (int ni = 0; ni < 4; ++ni)
        bfr[kk][ni] = *(const bf16x8*)&Bs[(wc * 64 + ni * 16 + frow) * 64 + col];
    }
    asm volatile("s_waitcnt lgkmcnt(0)" ::: "memory"); // frags in registers
    __builtin_amdgcn_sched_barrier(0);
    __builtin_amdgcn_s_barrier();                      // image free for restage
    __builtin_amdgcn_sched_barrier(0);

    if (t + 1 < nt) stage(t + 1);                      // overlaps with MFMA below

    __builtin_amdgcn_s_setprio(1);
    #pragma unroll
    for (int kk = 0; kk < 2; ++kk)
      #pragma unroll
      for (int mi = 0; mi < 4; ++mi)
        #pragma unroll
        for (int ni = 0; ni < 4; ++ni)
          acc[mi][ni] = __builtin_amdgcn_mfma_f32_16x16x32_bf16(af[kk][mi], bfr[kk][ni], acc[mi][ni], 0, 0, 0);
    __builtin_amdgcn_s_setprio(0);
  }

  // epilogue: C/D layout col=lane&15, row=(lane>>4)*4+reg
  const float* bias = nullptr;
  if (MODE == 0) bias = (w == 0) ? b0 : (w == 1) ? b1 : b2;

  #pragma unroll
  for (int mi = 0; mi < 4; ++mi) {
    #pragma unroll
    for (int ni = 0; ni < 4; ++ni) {
      const int row0 = brow0 + wr * 64 + mi * 16 + (lane >> 4) * 4;
      const int col = bcol0 + wc * 64 + ni * 16 + frow;
      if (MODE == 0) {
        const float bv = bias[col];
        if (w == 2) {
          unsigned short* Cb = (unsigned short*)C2;
          const int bb = row0 >> 11, s0 = row0 & 2047;
          ushort4 pk;
          pk.x = f2bf(acc[mi][ni][0] + bv);
          pk.y = f2bf(acc[mi][ni][1] + bv);
          pk.z = f2bf(acc[mi][ni][2] + bv);
          pk.w = f2bf(acc[mi][ni][3] + bv);
          *(ushort4*)&Cb[(size_t)bb * (1024 * 2048) + (size_t)col * 2048 + s0] = pk;
        } else {
          unsigned short* Cb = (unsigned short*)(w == 0 ? C0 : C1);
          #pragma unroll
          for (int r = 0; r < 4; ++r)
            Cb[(size_t)(row0 + r) * ldc + col] = f2bf(acc[mi][ni][r] + bv);
        }
      } else if (MODE == 2) {
        unsigned short* Cb = (unsigned short*)C0 + (size_t)bz * sC;
        #pragma unroll
        for (int r = 0; r < 4; ++r)
          Cb[(size_t)(row0 + r) * ldc + col] = f2bf(acc[mi][ni][r] * scale);
      } else {
        float* Cf = (float*)C0 + (size_t)bz * sC;
        #pragma unroll
        for (int r = 0; r < 4; ++r)
          Cf[(size_t)(row0 + r) * ldc + col] = acc[mi][ni][r];
      }
    }
  }
}

// in-place causal softmax, trimmed to the 128-col-rounded causal prefix
__global__ __launch_bounds__(256) void softmax_causal(unsigned short* __restrict__ Sc) {
  const int row = blockIdx.x;     // b*2048 + i
  const int i = row & 2047;
  const int nc = ((i >> 7) + 1) * 128;
  unsigned short* rp = Sc + (size_t)row * 2048;
  const int t = threadIdx.x;
  const int j0 = t * 8;
  const bool act = (j0 < nc);

  float v[8];
  if (act) {
    uint4 raw = ((const uint4*)rp)[t];
    unsigned us[8];
    us[0] = raw.x & 0xffffu; us[1] = raw.x >> 16;
    us[2] = raw.y & 0xffffu; us[3] = raw.y >> 16;
    us[4] = raw.z & 0xffffu; us[5] = raw.z >> 16;
    us[6] = raw.w & 0xffffu; us[7] = raw.w >> 16;
    #pragma unroll
    for (int e = 0; e < 8; ++e) v[e] = bf2f((unsigned short)us[e]);
  } else {
    #pragma unroll
    for (int e = 0; e < 8; ++e) v[e] = 0.f;
  }

  float m = -3.0e38f;
  if (act) {
    #pragma unroll
    for (int e = 0; e < 8; ++e) if (j0 + e <= i) m = fmaxf(m, v[e]);
  }
  #pragma unroll
  for (int o = 32; o > 0; o >>= 1) m = fmaxf(m, __shfl_xor(m, o));

  __shared__ float red[8];
  const int wid = t >> 6, lane = t & 63;
  if (lane == 0) red[wid] = m;
  __syncthreads();
  m = fmaxf(fmaxf(red[0], red[1]), fmaxf(red[2], red[3]));

  float ev[8];
  float s = 0.f;
  #pragma unroll
  for (int e = 0; e < 8; ++e) {
    float x = (act && j0 + e <= i) ? __expf(v[e] - m) : 0.f;
    ev[e] = x; s += x;
  }
  #pragma unroll
  for (int o = 32; o > 0; o >>= 1) s += __shfl_xor(s, o);
  if (lane == 0) red[4 + wid] = s;
  __syncthreads();
  s = red[4] + red[5] + red[6] + red[7];
  const float inv = 1.f / s;

  if (act) {
    uint4 outw;
    outw.x = (unsigned)f2bf(ev[0] * inv) | ((unsigned)f2bf(ev[1] * inv) << 16);
    outw.y = (unsigned)f2bf(ev[2] * inv) | ((unsigned)f2bf(ev[3] * inv) << 16);
    outw.z = (unsigned)f2bf(ev[4] * inv) | ((unsigned)f2bf(ev[5] * inv) << 16);
    outw.w = (unsigned)f2bf(ev[6] * inv) | ((unsigned)f2bf(ev[7] * inv) << 16);
    ((uint4*)rp)[t] = outw;
  }
}

// one launch converts x (2,097,152 float4) + 3 weights (262,144 float4 each)
__global__ __launch_bounds__(256) void cvt_all(
    const float4* __restrict__ x,
    const float4* __restrict__ w0, const float4* __restrict__ w1,
    const float4* __restrict__ w2,
    ushort4* __restrict__ xb, ushort4* __restrict__ wb) {
  const int idx = blockIdx.x * 256 + threadIdx.x;   // [0, 2883584)
  const float4* src; ushort4* dst; int off;
  if (idx < 2097152) { src = x; dst = xb; off = idx; }
  else {
    const int j = idx - 2097152;
    const int sel = j >> 18;                        // 262144 per weight
    src = (sel == 0) ? w0 : (sel == 1) ? w1 : w2;
    dst = wb + (size_t)sel * 262144;
    off = j & 262143;
  }
  float4 f = src[off];
  ushort4 o;
  o.x = f2bf(f.x); o.y = f2bf(f.y); o.z = f2bf(f.z); o.w = f2bf(f.w);
  dst[off] = o;
}

extern "C" void kernel_launch(void* const* d_in, const int* in_sizes, int n_in,
                              void* d_out, int out_size, void* d_ws, size_t ws_size,
                              hipStream_t stream) {
  const float* x  = (const float*)d_in[0];
  const float* Wk = (const float*)d_in[1];
  const float* bk = (const float*)d_in[2];
  const float* Wq = (const float*)d_in[3];
  const float* bq = (const float*)d_in[4];
  const float* Wv = (const float*)d_in[5];
  const float* bv = (const float*)d_in[6];
  float* out = (float*)d_out;

  char* ws = (char*)d_ws;
  unsigned short* xb = (unsigned short*)(ws + 0);          // 8192x1024 bf16  (16 MB)
  unsigned short* Wb = (unsigned short*)(ws + 16777216);   // 3 x 1024x1024   (6 MB)
  unsigned short* Kb = (unsigned short*)(ws + 23068672);   // 8192x1024       (16 MB)
  unsigned short* Qb = (unsigned short*)(ws + 39845888);   // 8192x1024       (16 MB)
  unsigned short* Vt = (unsigned short*)(ws + 56623104);   // 4 x 1024x2048   (16 MB)
  unsigned short* Sc = (unsigned short*)(ws + 73400320);   // 4 x 2048x2048   (32 MB)

  // converts (x + 3 weights, one launch)
  cvt_all<<<11264, 256, 0, stream>>>((const float4*)x, (const float4*)Wk,
                                     (const float4*)Wq, (const float4*)Wv,
                                     (ushort4*)xb, (ushort4*)Wb);

  // fused QKV: 1536 blocks, XCD-chunked row panels
  gemmC<0><<<1536, 256, 0, stream>>>(
      xb, 1024, 0, Wb, 1024, 0, Kb, 1024, 0, bk, bq, bv, Qb, Vt, 1024, 1.f);

  // scores = Q K^T / 32: exact causal lower-triangle grid (544 blocks)
  gemmC<2><<<544, 256, 0, stream>>>(
      Qb, 1024, 2048LL * 1024, Kb, 1024, 2048LL * 1024,
      Sc, 2048, 2048LL * 2048, nullptr, nullptr, nullptr, nullptr, nullptr, 1024, 0.03125f);

  softmax_causal<<<8192, 256, 0, stream>>>(Sc);

  // out = P @ V: 512 blocks, LPT, XCD-pinned batch (Vt L2-resident)
  gemmC<3><<<512, 256, 0, stream>>>(
      Sc, 2048, 2048LL * 2048, Vt, 2048, 1024LL * 2048,
      out, 1024, 2048LL * 1024, nullptr, nullptr, nullptr, nullptr, nullptr, 2048, 1.f);
}